// Round 11
// baseline (185.492 us; speedup 1.0000x reference)
//
#include <hip/hip_runtime.h>
#include <hip/hip_bf16.h>

// B=4, S=1024, E=1024, H=16, d=64 -> NH=64 heads. Out: [64,1024,1024] fp32.
// sparsemax(Q K^T) per head, SCALE=1.0. V chunk of the projection is dead.
//
// FRAGMENT-MAJOR workspace layout for K/Q hi/lo (round 10, kept):
// Chunk = (head n, 16-row/col block blk16, kc in {0,1}): 512 bf16 = 1 KB.
// Lane ln reads elements [ln*8, ln*8+8) of its chunk -> every MFMA fragment
// load is 1 KB CONTIGUOUS (64-line stride-128B gathers were the ~165 us wall
// of rounds 2-9: TA-transaction-serialized, layout-invariant).
// Element (col, d) of chunk (n, blk16, kc): lane = ((d&31)>>3)*16 + (col&15),
// j = d&7, with blk16 = col>>4, kc = d>>5.

typedef __attribute__((ext_vector_type(8))) short bf16x8;   // 8 bf16 = 4 VGPRs
typedef __attribute__((ext_vector_type(4))) float f32x4;

__device__ __forceinline__ ushort f2bf(float x) {           // RNE f32 -> bf16 bits
    uint u = __float_as_uint(x);
    u += 0x7FFFu + ((u >> 16) & 1u);
    return (ushort)(u >> 16);
}
__device__ __forceinline__ float bf2f(ushort h) {
    return __uint_as_float(((uint)h) << 16);
}

typedef const __attribute__((address_space(1))) unsigned int* gptr_t;
typedef __attribute__((address_space(3))) unsigned int* sptr_t;
__device__ __forceinline__ void gload_lds16(const void* g, void* l) {
    __builtin_amdgcn_global_load_lds((gptr_t)g, (sptr_t)l, 16, 0, 0);
}

// ---------------------------------------------------------------------------
// Kernel 0: fp32 -> split bf16 (hi = bf16(v), lo = bf16(v - hi)), elementwise.
// ---------------------------------------------------------------------------
__global__ __launch_bounds__(256)
void convert_split_kernel(const float* __restrict__ in, ushort* __restrict__ hi,
                          ushort* __restrict__ lo, int n4)
{
    int i = blockIdx.x * 256 + threadIdx.x;
    const int stride = gridDim.x * 256;
    for (; i < n4; i += stride) {
        float4 v = ((const float4*)in)[i];
        ushort4 h, l;
        h.x = f2bf(v.x); l.x = f2bf(v.x - bf2f(h.x));
        h.y = f2bf(v.y); l.y = f2bf(v.y - bf2f(h.y));
        h.z = f2bf(v.z); l.z = f2bf(v.z - bf2f(h.z));
        h.w = f2bf(v.w); l.w = f2bf(v.w - bf2f(h.w));
        ((ushort4*)hi)[i] = h;
        ((ushort4*)lo)[i] = l;
    }
}

// ---------------------------------------------------------------------------
// Kernel 1: projection GEMM via split-bf16 MFMA. GEMM core unchanged
// (round 3); epilogue scatters into the fragment-major layout above.
// ---------------------------------------------------------------------------
__global__ __launch_bounds__(512)
void proj_kernel(const ushort* __restrict__ xh, const ushort* __restrict__ xl,
                 const ushort* __restrict__ wh, const ushort* __restrict__ wl,
                 ushort* __restrict__ khi, ushort* __restrict__ klo,
                 ushort* __restrict__ qhi, ushort* __restrict__ qlo)
{
    __shared__ __align__(16) ushort Ah[128 * 64], Al[128 * 64];   // 16 KB each
    __shared__ __align__(16) ushort Bh[128 * 64], Bl[128 * 64];   // total 64 KB
    const int tid = threadIdx.x, w = tid >> 6, l = tid & 63;
    const int m0 = blockIdx.y * 128, c0 = blockIdx.x * 128;
    const int wr = w >> 2, wc = w & 3;          // wave -> 64m x 32c sub-tile
    const int lm = l & 15, lk = l >> 4;
    const int sslot = (l & 7) ^ (l >> 3);       // pre-swizzled source chunk

    f32x4 acc[4][2];
#pragma unroll
    for (int mf = 0; mf < 4; ++mf)
#pragma unroll
        for (int nf = 0; nf < 2; ++nf) acc[mf][nf] = (f32x4){0.f, 0.f, 0.f, 0.f};

    for (int k0 = 0; k0 < 1024; k0 += 64) {
        __syncthreads();                        // prev ds_reads done
#pragma unroll
        for (int i = 0; i < 2; ++i) {
            const int r = 16 * w + 8 * i + (l >> 3);
            const size_t ga = (size_t)(m0 + r) * 1024 + k0 + sslot * 8;
            const size_t gb = (size_t)(c0 + r) * 1024 + k0 + sslot * 8;
            const int lb = (16 * w + 8 * i) * 128;          // LDS byte base (uniform)
            gload_lds16(xh + ga, (char*)Ah + lb);
            gload_lds16(xl + ga, (char*)Al + lb);
            gload_lds16(wh + gb, (char*)Bh + lb);
            gload_lds16(wl + gb, (char*)Bl + lb);
        }
        __syncthreads();                        // vmcnt drained by barrier
#pragma unroll
        for (int kc = 0; kc < 2; ++kc) {
            bf16x8 a_h[4], a_l[4], b_h[2], b_l[2];
#pragma unroll
            for (int mf = 0; mf < 4; ++mf) {
                const int ra = wr * 64 + mf * 16 + lm;
                const int off = ra * 128 + ((kc * 4 + lk) ^ (ra & 7)) * 16;
                a_h[mf] = *(const bf16x8*)((const char*)Ah + off);
                a_l[mf] = *(const bf16x8*)((const char*)Al + off);
            }
#pragma unroll
            for (int nf = 0; nf < 2; ++nf) {
                const int rb = wc * 32 + nf * 16 + lm;
                const int off = rb * 128 + ((kc * 4 + lk) ^ (rb & 7)) * 16;
                b_h[nf] = *(const bf16x8*)((const char*)Bh + off);
                b_l[nf] = *(const bf16x8*)((const char*)Bl + off);
            }
#pragma unroll
            for (int mf = 0; mf < 4; ++mf)
#pragma unroll
                for (int nf = 0; nf < 2; ++nf) {
                    f32x4 a = acc[mf][nf];
                    a = __builtin_amdgcn_mfma_f32_16x16x32_bf16(a_h[mf], b_h[nf], a, 0, 0, 0);
                    a = __builtin_amdgcn_mfma_f32_16x16x32_bf16(a_l[mf], b_h[nf], a, 0, 0, 0);
                    a = __builtin_amdgcn_mfma_f32_16x16x32_bf16(a_h[mf], b_l[nf], a, 0, 0, 0);
                    acc[mf][nf] = a;
                }
        }
    }

    // epilogue: split-bf16, scatter into fragment-major K / Q buffers
#pragma unroll
    for (int mf = 0; mf < 4; ++mf)
#pragma unroll
        for (int nf = 0; nf < 2; ++nf) {
            const int c = c0 + wc * 32 + nf * 16 + lm;
            const int cc = c & 1023;
            ushort* dh = (c < 1024) ? khi : qhi;
            ushort* dl = (c < 1024) ? klo : qlo;
            const int d   = cc & 63;
            const int kc  = d >> 5;             // 32-wide k-half
            const int lkp = (d & 31) >> 3;      // k-slice within half
            const int j   = d & 7;              // elem within lane chunk
#pragma unroll
            for (int rg = 0; rg < 4; ++rg) {
                const int m = m0 + wr * 64 + mf * 16 + lk * 4 + rg;
                const int n = ((m >> 10) << 4) + (cc >> 6);
                const int s = m & 1023;
                const int sblk = s >> 4, lmp = s & 15;
                const size_t off = ((size_t)n << 16)
                                 + ((size_t)((sblk << 1) | kc) << 9)
                                 + (((lkp << 4) + lmp) << 3) + j;
                const float v = acc[mf][nf][rg];
                const ushort h = f2bf(v), lo_ = f2bf(v - bf2f(h));
                dh[off] = h;
                dl[off] = lo_;
            }
        }
}

// ---------------------------------------------------------------------------
// Kernel 2 (round 11): 32 q-rows/block, 16 waves (1024 thr), 2048 blocks.
// Wave wv: row-group rgrp = wv>>3 (rows r0+rgrp*16..+15), col-strip ws = wv&7
// (cols ws*128..+127). Per-wave work identical to round 10 (VGPR ~36), but:
//   - the 2 waves sharing a col-strip load IDENTICAL K fragments -> L1 hit,
//     L2 K-traffic halves; per-head K re-read 64 -> 32 blocks
//   - half the blocks -> half the barrier/max-phase instances
// Michelot exit is BLOCK-uniform: each lane tracks the summed support count
// of its row in BOTH groups (per-row counts are non-increasing, so the sum
// is stable iff both are) -> __all(st) identical in all 16 waves.
// Kept: fragment-major loads, swapped-operand MFMA (acc[nf][rg] =
// logits[q=lm][k=ws*128+nf*16+lk*4+rg]), tau0 = rowmax-1, float4 stores,
// XCD-chunked swizzle (2048 = 8 * 256).
// ---------------------------------------------------------------------------
__global__ __launch_bounds__(1024, 8)
void attn_sparsemax_kernel(const ushort* __restrict__ khi, const ushort* __restrict__ klo,
                           const ushort* __restrict__ qhi, const ushort* __restrict__ qlo,
                           float* __restrict__ out)
{
    __shared__ __align__(16) float pm[2][8][16];     // [grp][strip][row] maxes
    __shared__ __align__(16) float ps[2][2][8][16];  // ping-pong sums
    __shared__ __align__(16) float pc[2][2][8][16];  // ping-pong counts
    const int tid = threadIdx.x, wv = tid >> 6, ln = tid & 63;
    const int rgrp = wv >> 3, ws = wv & 7;
    const int bid = blockIdx.x;
    const int vb  = (bid & 7) * 256 + (bid >> 3);    // XCD-chunked remap
    const int n   = vb >> 5;                         // head 0..63
    const int r0  = (vb & 31) << 5;                  // q-row base (32 rows)
    const size_t hb = (size_t)n << 16;               // head base, elems
    const int lm = ln & 15, lk = ln >> 4;

    // Q fragments (B operand): chunk (n, (r0>>4)+rgrp, kc), 16 B/lane contiguous
    bf16x8 qh[2], ql[2];
    {
        const int blkq = ((r0 >> 4) + rgrp) << 1;
        const size_t qb = hb + ((size_t)blkq << 9) + ((size_t)ln << 3);
        qh[0] = *(const bf16x8*)(qhi + qb);
        qh[1] = *(const bf16x8*)(qhi + qb + 512);
        ql[0] = *(const bf16x8*)(qlo + qb);
        ql[1] = *(const bf16x8*)(qlo + qb + 512);
    }

    f32x4 acc[8];
#pragma unroll
    for (int nf = 0; nf < 8; ++nf) acc[nf] = (f32x4){0.f, 0.f, 0.f, 0.f};

    const int c0 = ws * 128;                         // this wave's 128 k-cols
    const size_t kb = hb + ((size_t)((c0 >> 4) << 1) << 9) + ((size_t)ln << 3);

#pragma unroll
    for (int nf = 0; nf < 8; ++nf) {
        const size_t o = kb + ((size_t)(nf << 1) << 9);
        bf16x8 kh0 = *(const bf16x8*)(khi + o);
        bf16x8 kh1 = *(const bf16x8*)(khi + o + 512);
        bf16x8 kl0 = *(const bf16x8*)(klo + o);
        bf16x8 kl1 = *(const bf16x8*)(klo + o + 512);
        f32x4 a = acc[nf];
        a = __builtin_amdgcn_mfma_f32_16x16x32_bf16(kh0, qh[0], a, 0, 0, 0);
        a = __builtin_amdgcn_mfma_f32_16x16x32_bf16(kh1, qh[1], a, 0, 0, 0);
        a = __builtin_amdgcn_mfma_f32_16x16x32_bf16(kl0, qh[0], a, 0, 0, 0);
        a = __builtin_amdgcn_mfma_f32_16x16x32_bf16(kl1, qh[1], a, 0, 0, 0);
        a = __builtin_amdgcn_mfma_f32_16x16x32_bf16(kh0, ql[0], a, 0, 0, 0);
        a = __builtin_amdgcn_mfma_f32_16x16x32_bf16(kh1, ql[1], a, 0, 0, 0);
        acc[nf] = a;
    }

    // ---- row max: 32 in-lane, 2 shfl hops, cross-strip via pm ----
    {
        float m = acc[0][0];
#pragma unroll
        for (int nf = 0; nf < 8; ++nf)
#pragma unroll
            for (int rg = 0; rg < 4; ++rg) m = fmaxf(m, acc[nf][rg]);
        m = fmaxf(m, __shfl_xor(m, 16));
        m = fmaxf(m, __shfl_xor(m, 32));
        if (ln < 16) pm[rgrp][ws][ln] = m;
    }
    __syncthreads();

    float tau;
    {
        float mx = fmaxf(pm[rgrp][lk][lm], pm[rgrp][lk + 4][lm]);
        mx = fmaxf(mx, __shfl_xor(mx, 16));
        mx = fmaxf(mx, __shfl_xor(mx, 32));
        tau = mx - 1.0f;
    }

    // ---- Michelot from tau0 = rowmax-1 (support tiny; ~2-3 passes) ----
    int buf = 0;
    float koldsum = 0.f;
    for (int it = 0; it < 32; ++it) {
        float sv = 0.f, cv = 0.f;
#pragma unroll
        for (int nf = 0; nf < 8; ++nf)
#pragma unroll
            for (int rg = 0; rg < 4; ++rg) {
                const bool p = acc[nf][rg] > tau;
                sv += p ? acc[nf][rg] : 0.f;
                cv += p ? 1.f : 0.f;
            }
        sv += __shfl_xor(sv, 16); cv += __shfl_xor(cv, 16);
        sv += __shfl_xor(sv, 32); cv += __shfl_xor(cv, 32);
        if (ln < 16) { ps[buf][rgrp][ws][ln] = sv; pc[buf][rgrp][ws][ln] = cv; }
        __syncthreads();
        float S  = ps[buf][rgrp][lk][lm]     + ps[buf][rgrp][lk + 4][lm];
        float C  = pc[buf][rgrp][lk][lm]     + pc[buf][rgrp][lk + 4][lm];
        float Co = pc[buf][rgrp ^ 1][lk][lm] + pc[buf][rgrp ^ 1][lk + 4][lm];
        S  += __shfl_xor(S, 16);  C  += __shfl_xor(C, 16);  Co += __shfl_xor(Co, 16);
        S  += __shfl_xor(S, 32);  C  += __shfl_xor(C, 32);  Co += __shfl_xor(Co, 32);
        const bool st = (C + Co == koldsum);   // both groups' rows stable
        koldsum = C + Co;
        tau = (S - 1.0f) / C;      // bit-identical when row converged
        buf ^= 1;
        if (__all(st)) break;      // block-uniform exit (all 32 rows stable)
    }

    // ---- fused relu write: native float4 per accumulator, cached stores ----
    float* orow = out + ((((size_t)n << 10) + r0 + (rgrp << 4) + lm) << 10)
                      + c0 + (lk << 2);
#pragma unroll
    for (int nf = 0; nf < 8; ++nf) {
        f32x4 o;
        o[0] = fmaxf(acc[nf][0] - tau, 0.f);
        o[1] = fmaxf(acc[nf][1] - tau, 0.f);
        o[2] = fmaxf(acc[nf][2] - tau, 0.f);
        o[3] = fmaxf(acc[nf][3] - tau, 0.f);
        *(f32x4*)(orow + nf * 16) = o;
    }
}

// ---------------------------------------------------------------------------
extern "C" void kernel_launch(void* const* d_in, const int* in_sizes, int n_in,
                              void* d_out, int out_size, void* d_ws, size_t ws_size,
                              hipStream_t stream) {
    const float* x = (const float*)d_in[0];          // [4096, 1024]
    const float* w = (const float*)d_in[1];          // [3072, 1024]
    float* out = (float*)d_out;                      // [64, 1024, 1024]

    const size_t HE = (size_t)64 * 1024 * 64;        // 4.19M elems per head buf
    const size_t XE = (size_t)4096 * 1024;           // x elems
    const size_t WE = (size_t)2048 * 1024;           // W' elems (rows 1024..3071)
    ushort* khi = (ushort*)d_ws;
    ushort* klo = khi + HE;
    ushort* qhi = klo + HE;
    ushort* qlo = qhi + HE;
    ushort* xh  = qlo + HE;
    ushort* xl  = xh + XE;
    ushort* wh  = xl + XE;
    ushort* wl  = wh + WE;                           // total ~58.7 MB of d_ws

    convert_split_kernel<<<2048, 256, 0, stream>>>(x, xh, xl, (int)(XE / 4));
    convert_split_kernel<<<2048, 256, 0, stream>>>(w + (size_t)1024 * 1024, wh, wl, (int)(WE / 4));
    proj_kernel<<<dim3(16, 32), 512, 0, stream>>>(xh, xl, wh, wl, khi, klo, qhi, qlo);
    attn_sparsemax_kernel<<<2048, 1024, 0, stream>>>(khi, klo, qhi, qlo, out);
}

// Round 12
// 169.901 us; speedup vs baseline: 1.0918x; 1.0918x over previous
//
#include <hip/hip_runtime.h>
#include <hip/hip_bf16.h>

// B=4, S=1024, E=1024, H=16, d=64 -> NH=64 heads. Out: [64,1024,1024] fp32.
// sparsemax(Q K^T) per head, SCALE=1.0. V chunk of the projection is dead.
//
// FRAGMENT-MAJOR workspace layout for K/Q hi/lo (round 10, kept):
// Chunk = (head n, 16-row/col block blk16, kc in {0,1}): 512 bf16 = 1 KB.
// Lane ln reads elements [ln*8, ln*8+8) of its chunk -> every MFMA fragment
// load is 1 KB CONTIGUOUS (64-line stride-128B gathers were the ~165 us wall
// of rounds 2-9: TA-transaction-serialized, layout-invariant).
// Element (col, d) of chunk (n, blk16, kc): lane = ((d&31)>>3)*16 + (col&15),
// j = d&7, with blk16 = col>>4, kc = d>>5.
//
// Round-12: revert to round-10 attn structure (512-thr blocks, uncoupled
// 16-row sparsemax — r6/r11 showed 1024-thr blocks lose phase diversity),
// with launch_bounds(512,8) for 4 blocks/CU, + fused convert kernel.

typedef __attribute__((ext_vector_type(8))) short bf16x8;   // 8 bf16 = 4 VGPRs
typedef __attribute__((ext_vector_type(4))) float f32x4;

__device__ __forceinline__ ushort f2bf(float x) {           // RNE f32 -> bf16 bits
    uint u = __float_as_uint(x);
    u += 0x7FFFu + ((u >> 16) & 1u);
    return (ushort)(u >> 16);
}
__device__ __forceinline__ float bf2f(ushort h) {
    return __uint_as_float(((uint)h) << 16);
}

typedef const __attribute__((address_space(1))) unsigned int* gptr_t;
typedef __attribute__((address_space(3))) unsigned int* sptr_t;
__device__ __forceinline__ void gload_lds16(const void* g, void* l) {
    __builtin_amdgcn_global_load_lds((gptr_t)g, (sptr_t)l, 16, 0, 0);
}

// ---------------------------------------------------------------------------
// Kernel 0: fp32 -> split bf16 for BOTH x and w' in one dispatch.
// ---------------------------------------------------------------------------
__global__ __launch_bounds__(256)
void convert_split2_kernel(const float* __restrict__ a, ushort* __restrict__ ah,
                           ushort* __restrict__ al, int na4,
                           const float* __restrict__ b, ushort* __restrict__ bh,
                           ushort* __restrict__ bl, int nb4)
{
    int i = blockIdx.x * 256 + threadIdx.x;
    const int stride = gridDim.x * 256;
    const int tot = na4 + nb4;
    for (; i < tot; i += stride) {
        const bool isa = i < na4;
        const int j = isa ? i : i - na4;
        float4 v = isa ? ((const float4*)a)[j] : ((const float4*)b)[j];
        ushort4 h, l;
        h.x = f2bf(v.x); l.x = f2bf(v.x - bf2f(h.x));
        h.y = f2bf(v.y); l.y = f2bf(v.y - bf2f(h.y));
        h.z = f2bf(v.z); l.z = f2bf(v.z - bf2f(h.z));
        h.w = f2bf(v.w); l.w = f2bf(v.w - bf2f(h.w));
        if (isa) { ((ushort4*)ah)[j] = h; ((ushort4*)al)[j] = l; }
        else     { ((ushort4*)bh)[j] = h; ((ushort4*)bl)[j] = l; }
    }
}

// ---------------------------------------------------------------------------
// Kernel 1: projection GEMM via split-bf16 MFMA. GEMM core unchanged
// (round 3); epilogue scatters into the fragment-major layout above.
// ---------------------------------------------------------------------------
__global__ __launch_bounds__(512)
void proj_kernel(const ushort* __restrict__ xh, const ushort* __restrict__ xl,
                 const ushort* __restrict__ wh, const ushort* __restrict__ wl,
                 ushort* __restrict__ khi, ushort* __restrict__ klo,
                 ushort* __restrict__ qhi, ushort* __restrict__ qlo)
{
    __shared__ __align__(16) ushort Ah[128 * 64], Al[128 * 64];   // 16 KB each
    __shared__ __align__(16) ushort Bh[128 * 64], Bl[128 * 64];   // total 64 KB
    const int tid = threadIdx.x, w = tid >> 6, l = tid & 63;
    const int m0 = blockIdx.y * 128, c0 = blockIdx.x * 128;
    const int wr = w >> 2, wc = w & 3;          // wave -> 64m x 32c sub-tile
    const int lm = l & 15, lk = l >> 4;
    const int sslot = (l & 7) ^ (l >> 3);       // pre-swizzled source chunk

    f32x4 acc[4][2];
#pragma unroll
    for (int mf = 0; mf < 4; ++mf)
#pragma unroll
        for (int nf = 0; nf < 2; ++nf) acc[mf][nf] = (f32x4){0.f, 0.f, 0.f, 0.f};

    for (int k0 = 0; k0 < 1024; k0 += 64) {
        __syncthreads();                        // prev ds_reads done
#pragma unroll
        for (int i = 0; i < 2; ++i) {
            const int r = 16 * w + 8 * i + (l >> 3);
            const size_t ga = (size_t)(m0 + r) * 1024 + k0 + sslot * 8;
            const size_t gb = (size_t)(c0 + r) * 1024 + k0 + sslot * 8;
            const int lb = (16 * w + 8 * i) * 128;          // LDS byte base (uniform)
            gload_lds16(xh + ga, (char*)Ah + lb);
            gload_lds16(xl + ga, (char*)Al + lb);
            gload_lds16(wh + gb, (char*)Bh + lb);
            gload_lds16(wl + gb, (char*)Bl + lb);
        }
        __syncthreads();                        // vmcnt drained by barrier
#pragma unroll
        for (int kc = 0; kc < 2; ++kc) {
            bf16x8 a_h[4], a_l[4], b_h[2], b_l[2];
#pragma unroll
            for (int mf = 0; mf < 4; ++mf) {
                const int ra = wr * 64 + mf * 16 + lm;
                const int off = ra * 128 + ((kc * 4 + lk) ^ (ra & 7)) * 16;
                a_h[mf] = *(const bf16x8*)((const char*)Ah + off);
                a_l[mf] = *(const bf16x8*)((const char*)Al + off);
            }
#pragma unroll
            for (int nf = 0; nf < 2; ++nf) {
                const int rb = wc * 32 + nf * 16 + lm;
                const int off = rb * 128 + ((kc * 4 + lk) ^ (rb & 7)) * 16;
                b_h[nf] = *(const bf16x8*)((const char*)Bh + off);
                b_l[nf] = *(const bf16x8*)((const char*)Bl + off);
            }
#pragma unroll
            for (int mf = 0; mf < 4; ++mf)
#pragma unroll
                for (int nf = 0; nf < 2; ++nf) {
                    f32x4 a = acc[mf][nf];
                    a = __builtin_amdgcn_mfma_f32_16x16x32_bf16(a_h[mf], b_h[nf], a, 0, 0, 0);
                    a = __builtin_amdgcn_mfma_f32_16x16x32_bf16(a_l[mf], b_h[nf], a, 0, 0, 0);
                    a = __builtin_amdgcn_mfma_f32_16x16x32_bf16(a_h[mf], b_l[nf], a, 0, 0, 0);
                    acc[mf][nf] = a;
                }
        }
    }

    // epilogue: split-bf16, scatter into fragment-major K / Q buffers
#pragma unroll
    for (int mf = 0; mf < 4; ++mf)
#pragma unroll
        for (int nf = 0; nf < 2; ++nf) {
            const int c = c0 + wc * 32 + nf * 16 + lm;
            const int cc = c & 1023;
            ushort* dh = (c < 1024) ? khi : qhi;
            ushort* dl = (c < 1024) ? klo : qlo;
            const int d   = cc & 63;
            const int kc  = d >> 5;             // 32-wide k-half
            const int lkp = (d & 31) >> 3;      // k-slice within half
            const int j   = d & 7;              // elem within lane chunk
#pragma unroll
            for (int rg = 0; rg < 4; ++rg) {
                const int m = m0 + wr * 64 + mf * 16 + lk * 4 + rg;
                const int n = ((m >> 10) << 4) + (cc >> 6);
                const int s = m & 1023;
                const int sblk = s >> 4, lmp = s & 15;
                const size_t off = ((size_t)n << 16)
                                 + ((size_t)((sblk << 1) | kc) << 9)
                                 + (((lkp << 4) + lmp) << 3) + j;
                const float v = acc[mf][nf][rg];
                const ushort h = f2bf(v), lo_ = f2bf(v - bf2f(h));
                dh[off] = h;
                dl[off] = lo_;
            }
        }
}

// ---------------------------------------------------------------------------
// Kernel 2 (round 12 = round 10 + 4 blocks/CU): swapped-operand fused logits
// MFMA + register sparsemax, fragment-major (1 KB/instr coalesced) loads.
// 512 threads = 8 waves, 16 q-rows/block, 4096 blocks, XCD-chunked swizzle.
// acc[nf][rg] = logits[q = r0+lm][k = c0 + nf*16 + lk*4 + rg] (HW-verified).
// Partials LDS is [wave][row] (conflict-free); cross-wave combine = 2 DS
// reads + 2 shfl per quantity (lk-split over the 8 wave partials).
// Kept: tau0 = rowmax-1 Michelot, uniform exit, float4 cached stores.
// ---------------------------------------------------------------------------
__global__ __launch_bounds__(512, 8)
void attn_sparsemax_kernel(const ushort* __restrict__ khi, const ushort* __restrict__ klo,
                           const ushort* __restrict__ qhi, const ushort* __restrict__ qlo,
                           float* __restrict__ out)
{
    __shared__ __align__(16) float pm[8][16];        // [wave][row] maxes
    __shared__ __align__(16) float ps[2][8][16];     // ping-pong sums
    __shared__ __align__(16) float pc[2][8][16];     // ping-pong counts
    const int tid = threadIdx.x, wv = tid >> 6, ln = tid & 63;
    const int bid = blockIdx.x;
    const int vb  = (bid & 7) * 512 + (bid >> 3);    // XCD-chunked remap
    const int n   = vb >> 6;                         // head 0..63
    const int r0  = (vb & 63) << 4;                  // q-row base
    const size_t hb = (size_t)n << 16;               // head base, elems
    const int lm = ln & 15, lk = ln >> 4;

    // Q fragments (B operand): chunk (n, r0>>4, kc), lane ln -> 16 B contiguous
    bf16x8 qh[2], ql[2];
    {
        const size_t qb = hb + ((size_t)((r0 >> 4) << 1) << 9) + ((size_t)ln << 3);
        qh[0] = *(const bf16x8*)(qhi + qb);
        qh[1] = *(const bf16x8*)(qhi + qb + 512);
        ql[0] = *(const bf16x8*)(qlo + qb);
        ql[1] = *(const bf16x8*)(qlo + qb + 512);
    }

    f32x4 acc[8];
#pragma unroll
    for (int nf = 0; nf < 8; ++nf) acc[nf] = (f32x4){0.f, 0.f, 0.f, 0.f};

    const int c0 = wv * 128;                         // this wave's 128 k-cols
    // K fragments (A operand): chunks (n, c0/16 + nf, kc)
    const size_t kb = hb + ((size_t)((c0 >> 4) << 1) << 9) + ((size_t)ln << 3);

#pragma unroll
    for (int nf = 0; nf < 8; ++nf) {
        const size_t o = kb + ((size_t)(nf << 1) << 9);
        bf16x8 kh0 = *(const bf16x8*)(khi + o);
        bf16x8 kh1 = *(const bf16x8*)(khi + o + 512);
        bf16x8 kl0 = *(const bf16x8*)(klo + o);
        bf16x8 kl1 = *(const bf16x8*)(klo + o + 512);
        f32x4 a = acc[nf];
        a = __builtin_amdgcn_mfma_f32_16x16x32_bf16(kh0, qh[0], a, 0, 0, 0);
        a = __builtin_amdgcn_mfma_f32_16x16x32_bf16(kh1, qh[1], a, 0, 0, 0);
        a = __builtin_amdgcn_mfma_f32_16x16x32_bf16(kl0, qh[0], a, 0, 0, 0);
        a = __builtin_amdgcn_mfma_f32_16x16x32_bf16(kl1, qh[1], a, 0, 0, 0);
        a = __builtin_amdgcn_mfma_f32_16x16x32_bf16(kh0, ql[0], a, 0, 0, 0);
        a = __builtin_amdgcn_mfma_f32_16x16x32_bf16(kh1, ql[1], a, 0, 0, 0);
        acc[nf] = a;
    }

    // ---- row max: 32 in-lane, 2 shfl hops, cross-wave via pm ----
    {
        float m = acc[0][0];
#pragma unroll
        for (int nf = 0; nf < 8; ++nf)
#pragma unroll
            for (int rg = 0; rg < 4; ++rg) m = fmaxf(m, acc[nf][rg]);
        m = fmaxf(m, __shfl_xor(m, 16));
        m = fmaxf(m, __shfl_xor(m, 32));
        if (ln < 16) pm[wv][ln] = m;
    }
    __syncthreads();

    float tau, kold = 0.f;
    {
        float mx = fmaxf(pm[lk][lm], pm[lk + 4][lm]);   // waves {lk, lk+4}
        mx = fmaxf(mx, __shfl_xor(mx, 16));             // merge lk^1
        mx = fmaxf(mx, __shfl_xor(mx, 32));             // merge lk^2
        tau = mx - 1.0f;
    }

    // ---- Michelot from tau0 = rowmax-1 (support tiny; ~2-3 passes) ----
    int buf = 0;
    for (int it = 0; it < 32; ++it) {
        float sv = 0.f, cv = 0.f;
#pragma unroll
        for (int nf = 0; nf < 8; ++nf)
#pragma unroll
            for (int rg = 0; rg < 4; ++rg) {
                const bool p = acc[nf][rg] > tau;
                sv += p ? acc[nf][rg] : 0.f;
                cv += p ? 1.f : 0.f;
            }
        sv += __shfl_xor(sv, 16); cv += __shfl_xor(cv, 16);
        sv += __shfl_xor(sv, 32); cv += __shfl_xor(cv, 32);
        if (ln < 16) { ps[buf][wv][ln] = sv; pc[buf][wv][ln] = cv; }
        __syncthreads();
        float S = ps[buf][lk][lm] + ps[buf][lk + 4][lm];
        float C = pc[buf][lk][lm] + pc[buf][lk + 4][lm];
        S += __shfl_xor(S, 16); C += __shfl_xor(C, 16);
        S += __shfl_xor(S, 32); C += __shfl_xor(C, 32);
        const bool st = (C == kold);
        kold = C;
        tau = (S - 1.0f) / C;      // bit-identical when row converged
        buf ^= 1;
        if (__all(st)) break;      // identical totals everywhere -> uniform exit
    }

    // ---- fused relu write: native float4 per accumulator, cached stores ----
    float* orow = out + ((((size_t)n << 10) + r0 + lm) << 10) + c0 + (lk << 2);
#pragma unroll
    for (int nf = 0; nf < 8; ++nf) {
        f32x4 o;
        o[0] = fmaxf(acc[nf][0] - tau, 0.f);
        o[1] = fmaxf(acc[nf][1] - tau, 0.f);
        o[2] = fmaxf(acc[nf][2] - tau, 0.f);
        o[3] = fmaxf(acc[nf][3] - tau, 0.f);
        *(f32x4*)(orow + nf * 16) = o;
    }
}

// ---------------------------------------------------------------------------
extern "C" void kernel_launch(void* const* d_in, const int* in_sizes, int n_in,
                              void* d_out, int out_size, void* d_ws, size_t ws_size,
                              hipStream_t stream) {
    const float* x = (const float*)d_in[0];          // [4096, 1024]
    const float* w = (const float*)d_in[1];          // [3072, 1024]
    float* out = (float*)d_out;                      // [64, 1024, 1024]

    const size_t HE = (size_t)64 * 1024 * 64;        // 4.19M elems per head buf
    const size_t XE = (size_t)4096 * 1024;           // x elems
    const size_t WE = (size_t)2048 * 1024;           // W' elems (rows 1024..3071)
    ushort* khi = (ushort*)d_ws;
    ushort* klo = khi + HE;
    ushort* qhi = klo + HE;
    ushort* qlo = qhi + HE;
    ushort* xh  = qlo + HE;
    ushort* xl  = xh + XE;
    ushort* wh  = xl + XE;
    ushort* wl  = wh + WE;                           // total ~58.7 MB of d_ws

    convert_split2_kernel<<<2048, 256, 0, stream>>>(
        x, xh, xl, (int)(XE / 4),
        w + (size_t)1024 * 1024, wh, wl, (int)(WE / 4));
    proj_kernel<<<dim3(16, 32), 512, 0, stream>>>(xh, xl, wh, wl, khi, klo, qhi, qlo);
    attn_sparsemax_kernel<<<4096, 512, 0, stream>>>(khi, klo, qhi, qlo, out);
}

// Round 13
// 153.879 us; speedup vs baseline: 1.2054x; 1.1041x over previous
//
#include <hip/hip_runtime.h>
#include <hip/hip_bf16.h>

// B=4, S=1024, E=1024, H=16, d=64 -> NH=64 heads. Out: [64,1024,1024] fp32.
// sparsemax(Q K^T) per head, SCALE=1.0. V chunk of the projection is dead.
//
// FRAGMENT-MAJOR workspace layout for K/Q hi/lo (round 10, kept):
// Chunk = (head n, 16-row/col block blk16, kc in {0,1}): 512 bf16 = 1 KB.
// Lane ln reads elements [ln*8, ln*8+8) of its chunk -> every MFMA fragment
// load is 1 KB CONTIGUOUS (64-line stride-128B gathers were the ~165 us wall
// of rounds 2-9: TA-transaction-serialized, layout-invariant).
//
// Round-13: attn waves compute 32 rows x 128 cols (2 acc groups share the
// same K fragments) -> per-head K re-reads 64 -> 32 blocks, L2 K-traffic
// 2 GB -> 1 GB. Blocks stay 512-thr/8-wave (r6/r11: 1024-thr blocks lose
// phase diversity). VGPR kept ~120 (< 128 cap of launch_bounds(512,4)) by
// splitting the nf step: kh products first, kl reloaded into same regs.

typedef __attribute__((ext_vector_type(8))) short bf16x8;   // 8 bf16 = 4 VGPRs
typedef __attribute__((ext_vector_type(4))) float f32x4;

__device__ __forceinline__ ushort f2bf(float x) {           // RNE f32 -> bf16 bits
    uint u = __float_as_uint(x);
    u += 0x7FFFu + ((u >> 16) & 1u);
    return (ushort)(u >> 16);
}
__device__ __forceinline__ float bf2f(ushort h) {
    return __uint_as_float(((uint)h) << 16);
}

typedef const __attribute__((address_space(1))) unsigned int* gptr_t;
typedef __attribute__((address_space(3))) unsigned int* sptr_t;
__device__ __forceinline__ void gload_lds16(const void* g, void* l) {
    __builtin_amdgcn_global_load_lds((gptr_t)g, (sptr_t)l, 16, 0, 0);
}

// ---------------------------------------------------------------------------
// Kernel 0: fp32 -> split bf16 for BOTH x and w' in one dispatch.
// ---------------------------------------------------------------------------
__global__ __launch_bounds__(256)
void convert_split2_kernel(const float* __restrict__ a, ushort* __restrict__ ah,
                           ushort* __restrict__ al, int na4,
                           const float* __restrict__ b, ushort* __restrict__ bh,
                           ushort* __restrict__ bl, int nb4)
{
    int i = blockIdx.x * 256 + threadIdx.x;
    const int stride = gridDim.x * 256;
    const int tot = na4 + nb4;
    for (; i < tot; i += stride) {
        const bool isa = i < na4;
        const int j = isa ? i : i - na4;
        float4 v = isa ? ((const float4*)a)[j] : ((const float4*)b)[j];
        ushort4 h, l;
        h.x = f2bf(v.x); l.x = f2bf(v.x - bf2f(h.x));
        h.y = f2bf(v.y); l.y = f2bf(v.y - bf2f(h.y));
        h.z = f2bf(v.z); l.z = f2bf(v.z - bf2f(h.z));
        h.w = f2bf(v.w); l.w = f2bf(v.w - bf2f(h.w));
        if (isa) { ((ushort4*)ah)[j] = h; ((ushort4*)al)[j] = l; }
        else     { ((ushort4*)bh)[j] = h; ((ushort4*)bl)[j] = l; }
    }
}

// ---------------------------------------------------------------------------
// Kernel 1: projection GEMM via split-bf16 MFMA (unchanged from round 3);
// epilogue scatters into the fragment-major layout.
// ---------------------------------------------------------------------------
__global__ __launch_bounds__(512)
void proj_kernel(const ushort* __restrict__ xh, const ushort* __restrict__ xl,
                 const ushort* __restrict__ wh, const ushort* __restrict__ wl,
                 ushort* __restrict__ khi, ushort* __restrict__ klo,
                 ushort* __restrict__ qhi, ushort* __restrict__ qlo)
{
    __shared__ __align__(16) ushort Ah[128 * 64], Al[128 * 64];   // 16 KB each
    __shared__ __align__(16) ushort Bh[128 * 64], Bl[128 * 64];   // total 64 KB
    const int tid = threadIdx.x, w = tid >> 6, l = tid & 63;
    const int m0 = blockIdx.y * 128, c0 = blockIdx.x * 128;
    const int wr = w >> 2, wc = w & 3;          // wave -> 64m x 32c sub-tile
    const int lm = l & 15, lk = l >> 4;
    const int sslot = (l & 7) ^ (l >> 3);       // pre-swizzled source chunk

    f32x4 acc[4][2];
#pragma unroll
    for (int mf = 0; mf < 4; ++mf)
#pragma unroll
        for (int nf = 0; nf < 2; ++nf) acc[mf][nf] = (f32x4){0.f, 0.f, 0.f, 0.f};

    for (int k0 = 0; k0 < 1024; k0 += 64) {
        __syncthreads();                        // prev ds_reads done
#pragma unroll
        for (int i = 0; i < 2; ++i) {
            const int r = 16 * w + 8 * i + (l >> 3);
            const size_t ga = (size_t)(m0 + r) * 1024 + k0 + sslot * 8;
            const size_t gb = (size_t)(c0 + r) * 1024 + k0 + sslot * 8;
            const int lb = (16 * w + 8 * i) * 128;          // LDS byte base (uniform)
            gload_lds16(xh + ga, (char*)Ah + lb);
            gload_lds16(xl + ga, (char*)Al + lb);
            gload_lds16(wh + gb, (char*)Bh + lb);
            gload_lds16(wl + gb, (char*)Bl + lb);
        }
        __syncthreads();                        // vmcnt drained by barrier
#pragma unroll
        for (int kc = 0; kc < 2; ++kc) {
            bf16x8 a_h[4], a_l[4], b_h[2], b_l[2];
#pragma unroll
            for (int mf = 0; mf < 4; ++mf) {
                const int ra = wr * 64 + mf * 16 + lm;
                const int off = ra * 128 + ((kc * 4 + lk) ^ (ra & 7)) * 16;
                a_h[mf] = *(const bf16x8*)((const char*)Ah + off);
                a_l[mf] = *(const bf16x8*)((const char*)Al + off);
            }
#pragma unroll
            for (int nf = 0; nf < 2; ++nf) {
                const int rb = wc * 32 + nf * 16 + lm;
                const int off = rb * 128 + ((kc * 4 + lk) ^ (rb & 7)) * 16;
                b_h[nf] = *(const bf16x8*)((const char*)Bh + off);
                b_l[nf] = *(const bf16x8*)((const char*)Bl + off);
            }
#pragma unroll
            for (int mf = 0; mf < 4; ++mf)
#pragma unroll
                for (int nf = 0; nf < 2; ++nf) {
                    f32x4 a = acc[mf][nf];
                    a = __builtin_amdgcn_mfma_f32_16x16x32_bf16(a_h[mf], b_h[nf], a, 0, 0, 0);
                    a = __builtin_amdgcn_mfma_f32_16x16x32_bf16(a_l[mf], b_h[nf], a, 0, 0, 0);
                    a = __builtin_amdgcn_mfma_f32_16x16x32_bf16(a_h[mf], b_l[nf], a, 0, 0, 0);
                    acc[mf][nf] = a;
                }
        }
    }

    // epilogue: split-bf16, scatter into fragment-major K / Q buffers
#pragma unroll
    for (int mf = 0; mf < 4; ++mf)
#pragma unroll
        for (int nf = 0; nf < 2; ++nf) {
            const int c = c0 + wc * 32 + nf * 16 + lm;
            const int cc = c & 1023;
            ushort* dh = (c < 1024) ? khi : qhi;
            ushort* dl = (c < 1024) ? klo : qlo;
            const int d   = cc & 63;
            const int kc  = d >> 5;             // 32-wide k-half
            const int lkp = (d & 31) >> 3;      // k-slice within half
            const int j   = d & 7;              // elem within lane chunk
#pragma unroll
            for (int rg = 0; rg < 4; ++rg) {
                const int m = m0 + wr * 64 + mf * 16 + lk * 4 + rg;
                const int n = ((m >> 10) << 4) + (cc >> 6);
                const int s = m & 1023;
                const int sblk = s >> 4, lmp = s & 15;
                const size_t off = ((size_t)n << 16)
                                 + ((size_t)((sblk << 1) | kc) << 9)
                                 + (((lkp << 4) + lmp) << 3) + j;
                const float v = acc[mf][nf][rg];
                const ushort h = f2bf(v), lo_ = f2bf(v - bf2f(h));
                dh[off] = h;
                dl[off] = lo_;
            }
        }
}

// ---------------------------------------------------------------------------
// Kernel 2 (round 13): 32 rows x 1024 cols per block, 512 thr = 8 waves.
// Wave wv covers cols wv*128, BOTH 16-row groups (acc[2][8], same K frags).
// acc[g][nf][rg] = logits[q=r0+g*16+lm][k=wv*128+nf*16+lk*4+rg].
// nf step split to cap VGPR: load kh (8 VGPR) -> 8 MFMAs, reload kl into
// same regs -> 4 MFMAs. Michelot: joint 2-row per lane, block-uniform exit
// via summed support counts (per-row non-increasing => sum stable iff both).
// Kept: fragment-major loads, tau0=rowmax-1, float4 stores, XCD swizzle.
// ---------------------------------------------------------------------------
__global__ __launch_bounds__(512, 4)
void attn_sparsemax_kernel(const ushort* __restrict__ khi, const ushort* __restrict__ klo,
                           const ushort* __restrict__ qhi, const ushort* __restrict__ qlo,
                           float* __restrict__ out)
{
    __shared__ __align__(16) float pm[2][8][16];     // [grp][wave][row] maxes
    __shared__ __align__(16) float ps[2][2][8][16];  // ping-pong sums
    __shared__ __align__(16) float pc[2][2][8][16];  // ping-pong counts
    const int tid = threadIdx.x, wv = tid >> 6, ln = tid & 63;
    const int bid = blockIdx.x;
    const int vb  = (bid & 7) * 256 + (bid >> 3);    // XCD-chunked remap (2048=8*256)
    const int n   = vb >> 5;                         // head 0..63
    const int r0  = (vb & 31) << 5;                  // q-row base (32 rows)
    const size_t hb = (size_t)n << 16;               // head base, elems
    const int lm = ln & 15, lk = ln >> 4;

    // Q fragments (B operand), both 16-row groups: chunk (n, (r0>>4)+g, kc)
    bf16x8 qh[2][2], ql[2][2];                       // [grp][kc] : 32 VGPR
#pragma unroll
    for (int g = 0; g < 2; ++g) {
        const size_t qb = hb + ((size_t)(((r0 >> 4) + g) << 1) << 9) + ((size_t)ln << 3);
        qh[g][0] = *(const bf16x8*)(qhi + qb);
        qh[g][1] = *(const bf16x8*)(qhi + qb + 512);
        ql[g][0] = *(const bf16x8*)(qlo + qb);
        ql[g][1] = *(const bf16x8*)(qlo + qb + 512);
    }

    f32x4 acc[2][8];                                 // 64 VGPR
#pragma unroll
    for (int g = 0; g < 2; ++g)
#pragma unroll
        for (int nf = 0; nf < 8; ++nf) acc[g][nf] = (f32x4){0.f, 0.f, 0.f, 0.f};

    const int c0 = wv * 128;                         // this wave's 128 k-cols
    const size_t kb = hb + ((size_t)((c0 >> 4) << 1) << 9) + ((size_t)ln << 3);

#pragma unroll
    for (int nf = 0; nf < 8; ++nf) {
        const size_t o = kb + ((size_t)(nf << 1) << 9);
        {   // hi K fragments: products hh (both kc) and h*ql
            bf16x8 k0 = *(const bf16x8*)(khi + o);
            bf16x8 k1 = *(const bf16x8*)(khi + o + 512);
#pragma unroll
            for (int g = 0; g < 2; ++g) {
                f32x4 a = acc[g][nf];
                a = __builtin_amdgcn_mfma_f32_16x16x32_bf16(k0, qh[g][0], a, 0, 0, 0);
                a = __builtin_amdgcn_mfma_f32_16x16x32_bf16(k1, qh[g][1], a, 0, 0, 0);
                a = __builtin_amdgcn_mfma_f32_16x16x32_bf16(k0, ql[g][0], a, 0, 0, 0);
                a = __builtin_amdgcn_mfma_f32_16x16x32_bf16(k1, ql[g][1], a, 0, 0, 0);
                acc[g][nf] = a;
            }
        }
        {   // lo K fragments (reuse regs): products lh
            bf16x8 k0 = *(const bf16x8*)(klo + o);
            bf16x8 k1 = *(const bf16x8*)(klo + o + 512);
#pragma unroll
            for (int g = 0; g < 2; ++g) {
                f32x4 a = acc[g][nf];
                a = __builtin_amdgcn_mfma_f32_16x16x32_bf16(k0, qh[g][0], a, 0, 0, 0);
                a = __builtin_amdgcn_mfma_f32_16x16x32_bf16(k1, qh[g][1], a, 0, 0, 0);
                acc[g][nf] = a;
            }
        }
    }

    // ---- row maxes (both groups, paired chains) ----
    {
        float m0v = acc[0][0][0], m1v = acc[1][0][0];
#pragma unroll
        for (int nf = 0; nf < 8; ++nf)
#pragma unroll
            for (int rg = 0; rg < 4; ++rg) {
                m0v = fmaxf(m0v, acc[0][nf][rg]);
                m1v = fmaxf(m1v, acc[1][nf][rg]);
            }
        m0v = fmaxf(m0v, __shfl_xor(m0v, 16)); m1v = fmaxf(m1v, __shfl_xor(m1v, 16));
        m0v = fmaxf(m0v, __shfl_xor(m0v, 32)); m1v = fmaxf(m1v, __shfl_xor(m1v, 32));
        if (ln < 16) { pm[0][wv][ln] = m0v; pm[1][wv][ln] = m1v; }
    }
    __syncthreads();

    float tau[2];
#pragma unroll
    for (int g = 0; g < 2; ++g) {
        float mx = fmaxf(pm[g][lk][lm], pm[g][lk + 4][lm]);
        mx = fmaxf(mx, __shfl_xor(mx, 16));
        mx = fmaxf(mx, __shfl_xor(mx, 32));
        tau[g] = mx - 1.0f;
    }

    // ---- Michelot from tau0 = rowmax-1, joint over both groups ----
    int buf = 0;
    float koldsum = 0.f;
    for (int it = 0; it < 32; ++it) {
        float sv[2] = {0.f, 0.f}, cv[2] = {0.f, 0.f};
#pragma unroll
        for (int g = 0; g < 2; ++g)
#pragma unroll
            for (int nf = 0; nf < 8; ++nf)
#pragma unroll
                for (int rg = 0; rg < 4; ++rg) {
                    const bool p = acc[g][nf][rg] > tau[g];
                    sv[g] += p ? acc[g][nf][rg] : 0.f;
                    cv[g] += p ? 1.f : 0.f;
                }
#pragma unroll
        for (int g = 0; g < 2; ++g) {
            sv[g] += __shfl_xor(sv[g], 16); cv[g] += __shfl_xor(cv[g], 16);
            sv[g] += __shfl_xor(sv[g], 32); cv[g] += __shfl_xor(cv[g], 32);
        }
        if (ln < 16) {
#pragma unroll
            for (int g = 0; g < 2; ++g) {
                ps[buf][g][wv][ln] = sv[g];
                pc[buf][g][wv][ln] = cv[g];
            }
        }
        __syncthreads();
        float S[2], C[2];
#pragma unroll
        for (int g = 0; g < 2; ++g) {
            float Sg = ps[buf][g][lk][lm] + ps[buf][g][lk + 4][lm];
            float Cg = pc[buf][g][lk][lm] + pc[buf][g][lk + 4][lm];
            Sg += __shfl_xor(Sg, 16); Cg += __shfl_xor(Cg, 16);
            Sg += __shfl_xor(Sg, 32); Cg += __shfl_xor(Cg, 32);
            S[g] = Sg; C[g] = Cg;
        }
        const float csum = C[0] + C[1];
        const bool st = (csum == koldsum);   // both rows stable (non-increasing)
        koldsum = csum;
#pragma unroll
        for (int g = 0; g < 2; ++g)
            tau[g] = (S[g] - 1.0f) / C[g];   // bit-identical when converged
        buf ^= 1;
        if (__all(st)) break;                // block-uniform exit
    }

    // ---- fused relu write: native float4 per accumulator, cached stores ----
#pragma unroll
    for (int g = 0; g < 2; ++g) {
        float* orow = out + ((((size_t)n << 10) + r0 + (g << 4) + lm) << 10)
                          + c0 + (lk << 2);
#pragma unroll
        for (int nf = 0; nf < 8; ++nf) {
            f32x4 o;
            o[0] = fmaxf(acc[g][nf][0] - tau[g], 0.f);
            o[1] = fmaxf(acc[g][nf][1] - tau[g], 0.f);
            o[2] = fmaxf(acc[g][nf][2] - tau[g], 0.f);
            o[3] = fmaxf(acc[g][nf][3] - tau[g], 0.f);
            *(f32x4*)(orow + nf * 16) = o;
        }
    }
}

// ---------------------------------------------------------------------------
extern "C" void kernel_launch(void* const* d_in, const int* in_sizes, int n_in,
                              void* d_out, int out_size, void* d_ws, size_t ws_size,
                              hipStream_t stream) {
    const float* x = (const float*)d_in[0];          // [4096, 1024]
    const float* w = (const float*)d_in[1];          // [3072, 1024]
    float* out = (float*)d_out;                      // [64, 1024, 1024]

    const size_t HE = (size_t)64 * 1024 * 64;        // 4.19M elems per head buf
    const size_t XE = (size_t)4096 * 1024;           // x elems
    const size_t WE = (size_t)2048 * 1024;           // W' elems (rows 1024..3071)
    ushort* khi = (ushort*)d_ws;
    ushort* klo = khi + HE;
    ushort* qhi = klo + HE;
    ushort* qlo = qhi + HE;
    ushort* xh  = qlo + HE;
    ushort* xl  = xh + XE;
    ushort* wh  = xl + XE;
    ushort* wl  = wh + WE;                           // total ~58.7 MB of d_ws

    convert_split2_kernel<<<2048, 256, 0, stream>>>(
        x, xh, xl, (int)(XE / 4),
        w + (size_t)1024 * 1024, wh, wl, (int)(WE / 4));
    proj_kernel<<<dim3(16, 32), 512, 0, stream>>>(xh, xl, wh, wl, khi, klo, qhi, qlo);
    attn_sparsemax_kernel<<<2048, 512, 0, stream>>>(khi, klo, qhi, qlo, out);
}

// Round 14
// 147.558 us; speedup vs baseline: 1.2571x; 1.0428x over previous
//
#include <hip/hip_runtime.h>
#include <hip/hip_bf16.h>

// B=4, S=1024, E=1024, H=16, d=64 -> NH=64 heads. Out: [64,1024,1024] fp32.
// sparsemax(Q K^T) per head, SCALE=1.0. V chunk of the projection is dead.
//
// Round-14: Q/K stored as 2-LEVEL INT8 (qa + qb/256, scale 6/128), fragment-
// major for mfma_i32_16x16x64_i8 (K=64 = all of d in ONE instruction).
// logits = C1*(P_aa + (P_ab+P_ba)/256 + P_bb/65536), C1=(6/128)^2; integer
// accumulation is exact, quantization error std ~4e-4 on logits.
// i8 chunk = (head n, 16-seq block blk16): 16 cols x 64 d = 1024 B;
// element (s, d) at byte (d>>4)*256 + (s&15)*16 + (d&15); lane ln reads
// bytes [ln*16, ln*16+16) -> coalesced 1 KB per fragment load, and A/B use
// mirrored placements (same-loader permutation-invariance, HW-proven shape).

typedef __attribute__((ext_vector_type(8))) short bf16x8;   // 8 bf16 = 4 VGPRs
typedef __attribute__((ext_vector_type(4))) float f32x4;
typedef __attribute__((ext_vector_type(4))) int   i32x4;

__device__ __forceinline__ ushort f2bf(float x) {           // RNE f32 -> bf16 bits
    uint u = __float_as_uint(x);
    u += 0x7FFFu + ((u >> 16) & 1u);
    return (ushort)(u >> 16);
}
__device__ __forceinline__ float bf2f(ushort h) {
    return __uint_as_float(((uint)h) << 16);
}

typedef const __attribute__((address_space(1))) unsigned int* gptr_t;
typedef __attribute__((address_space(3))) unsigned int* sptr_t;
__device__ __forceinline__ void gload_lds16(const void* g, void* l) {
    __builtin_amdgcn_global_load_lds((gptr_t)g, (sptr_t)l, 16, 0, 0);
}

#define QSCALE_INV 21.333333333f    // 128/6
#define QC1 0.002197265625f         // (6/128)^2

// ---------------------------------------------------------------------------
// Kernel 0: fp32 -> split bf16 for BOTH x and w' in one dispatch.
// ---------------------------------------------------------------------------
__global__ __launch_bounds__(256)
void convert_split2_kernel(const float* __restrict__ a, ushort* __restrict__ ah,
                           ushort* __restrict__ al, int na4,
                           const float* __restrict__ b, ushort* __restrict__ bh,
                           ushort* __restrict__ bl, int nb4)
{
    int i = blockIdx.x * 256 + threadIdx.x;
    const int stride = gridDim.x * 256;
    const int tot = na4 + nb4;
    for (; i < tot; i += stride) {
        const bool isa = i < na4;
        const int j = isa ? i : i - na4;
        float4 v = isa ? ((const float4*)a)[j] : ((const float4*)b)[j];
        ushort4 h, l;
        h.x = f2bf(v.x); l.x = f2bf(v.x - bf2f(h.x));
        h.y = f2bf(v.y); l.y = f2bf(v.y - bf2f(h.y));
        h.z = f2bf(v.z); l.z = f2bf(v.z - bf2f(h.z));
        h.w = f2bf(v.w); l.w = f2bf(v.w - bf2f(h.w));
        if (isa) { ((ushort4*)ah)[j] = h; ((ushort4*)al)[j] = l; }
        else     { ((ushort4*)bh)[j] = h; ((ushort4*)bl)[j] = l; }
    }
}

// ---------------------------------------------------------------------------
// Kernel 1: projection GEMM via split-bf16 MFMA (core unchanged from round 3);
// epilogue quantizes fp32 acc to 2-level i8 and scatters fragment-major.
// ---------------------------------------------------------------------------
__global__ __launch_bounds__(512)
void proj_kernel(const ushort* __restrict__ xh, const ushort* __restrict__ xl,
                 const ushort* __restrict__ wh, const ushort* __restrict__ wl,
                 signed char* __restrict__ kA, signed char* __restrict__ kB,
                 signed char* __restrict__ qA, signed char* __restrict__ qB)
{
    __shared__ __align__(16) ushort Ah[128 * 64], Al[128 * 64];   // 16 KB each
    __shared__ __align__(16) ushort Bh[128 * 64], Bl[128 * 64];   // total 64 KB
    const int tid = threadIdx.x, w = tid >> 6, l = tid & 63;
    const int m0 = blockIdx.y * 128, c0 = blockIdx.x * 128;
    const int wr = w >> 2, wc = w & 3;          // wave -> 64m x 32c sub-tile
    const int lm = l & 15, lk = l >> 4;
    const int sslot = (l & 7) ^ (l >> 3);       // pre-swizzled source chunk

    f32x4 acc[4][2];
#pragma unroll
    for (int mf = 0; mf < 4; ++mf)
#pragma unroll
        for (int nf = 0; nf < 2; ++nf) acc[mf][nf] = (f32x4){0.f, 0.f, 0.f, 0.f};

    for (int k0 = 0; k0 < 1024; k0 += 64) {
        __syncthreads();                        // prev ds_reads done
#pragma unroll
        for (int i = 0; i < 2; ++i) {
            const int r = 16 * w + 8 * i + (l >> 3);
            const size_t ga = (size_t)(m0 + r) * 1024 + k0 + sslot * 8;
            const size_t gb = (size_t)(c0 + r) * 1024 + k0 + sslot * 8;
            const int lb = (16 * w + 8 * i) * 128;          // LDS byte base (uniform)
            gload_lds16(xh + ga, (char*)Ah + lb);
            gload_lds16(xl + ga, (char*)Al + lb);
            gload_lds16(wh + gb, (char*)Bh + lb);
            gload_lds16(wl + gb, (char*)Bl + lb);
        }
        __syncthreads();                        // vmcnt drained by barrier
#pragma unroll
        for (int kc = 0; kc < 2; ++kc) {
            bf16x8 a_h[4], a_l[4], b_h[2], b_l[2];
#pragma unroll
            for (int mf = 0; mf < 4; ++mf) {
                const int ra = wr * 64 + mf * 16 + lm;
                const int off = ra * 128 + ((kc * 4 + lk) ^ (ra & 7)) * 16;
                a_h[mf] = *(const bf16x8*)((const char*)Ah + off);
                a_l[mf] = *(const bf16x8*)((const char*)Al + off);
            }
#pragma unroll
            for (int nf = 0; nf < 2; ++nf) {
                const int rb = wc * 32 + nf * 16 + lm;
                const int off = rb * 128 + ((kc * 4 + lk) ^ (rb & 7)) * 16;
                b_h[nf] = *(const bf16x8*)((const char*)Bh + off);
                b_l[nf] = *(const bf16x8*)((const char*)Bl + off);
            }
#pragma unroll
            for (int mf = 0; mf < 4; ++mf)
#pragma unroll
                for (int nf = 0; nf < 2; ++nf) {
                    f32x4 a = acc[mf][nf];
                    a = __builtin_amdgcn_mfma_f32_16x16x32_bf16(a_h[mf], b_h[nf], a, 0, 0, 0);
                    a = __builtin_amdgcn_mfma_f32_16x16x32_bf16(a_l[mf], b_h[nf], a, 0, 0, 0);
                    a = __builtin_amdgcn_mfma_f32_16x16x32_bf16(a_h[mf], b_l[nf], a, 0, 0, 0);
                    acc[mf][nf] = a;
                }
        }
    }

    // epilogue: 2-level i8 quantize, scatter into fragment-major buffers
#pragma unroll
    for (int mf = 0; mf < 4; ++mf)
#pragma unroll
        for (int nf = 0; nf < 2; ++nf) {
            const int c = c0 + wc * 32 + nf * 16 + lm;
            const int cc = c & 1023;
            signed char* dA = (c < 1024) ? kA : qA;
            signed char* dB = (c < 1024) ? kB : qB;
            const int d  = cc & 63;
            const int hd = cc >> 6;
#pragma unroll
            for (int rg = 0; rg < 4; ++rg) {
                const int m = m0 + wr * 64 + mf * 16 + lk * 4 + rg;
                const int n = ((m >> 10) << 4) + hd;
                const int s = m & 1023;
                const size_t off = ((size_t)n << 16) + ((size_t)(s >> 4) << 10)
                                 + ((d >> 4) << 8) + ((s & 15) << 4) + (d & 15);
                float t = acc[mf][nf][rg] * QSCALE_INV;
                float a = rintf(t); a = fminf(127.f, fmaxf(-127.f, a));
                float r = (t - a) * 256.f;
                float b = rintf(r); b = fminf(127.f, fmaxf(-127.f, b));
                dA[off] = (signed char)(int)a;
                dB[off] = (signed char)(int)b;
            }
        }
}

// ---------------------------------------------------------------------------
// Kernel 2 (round 14): i8 logits MFMA + register sparsemax, r13 skeleton.
// 32 rows x 1024 cols per block, 512 thr = 8 waves, 2048 blocks, XCD swizzle.
// Wave wv covers cols wv*128, both 16-row groups share K fragments.
// Per (g,nf): one i8 fragment pair (ka,kb 16 B/lane) covers ALL d=64;
// 4 x mfma_i32_16x16x64_i8 (aa; ba; ab chained; bb) -> exact integer dots;
// combine to f32: acc = C1*(P_aa + P_mix/256 + P_bb/65536).
// acc[g][nf][rg] = logits[q=r0+g*16+lm][k=wv*128+nf*16+lk*4+rg] (C/D map
// dtype-independent, HW-verified). Sparsemax identical to r13.
// ---------------------------------------------------------------------------
__global__ __launch_bounds__(512, 4)
void attn_sparsemax_kernel(const signed char* __restrict__ kA, const signed char* __restrict__ kB,
                           const signed char* __restrict__ qA, const signed char* __restrict__ qB,
                           float* __restrict__ out)
{
    __shared__ __align__(16) float pm[2][8][16];     // [grp][wave][row] maxes
    __shared__ __align__(16) float ps[2][2][8][16];  // ping-pong sums
    __shared__ __align__(16) float pc[2][2][8][16];  // ping-pong counts
    const int tid = threadIdx.x, wv = tid >> 6, ln = tid & 63;
    const int bid = blockIdx.x;
    const int vb  = (bid & 7) * 256 + (bid >> 3);    // XCD-chunked remap (2048=8*256)
    const int n   = vb >> 5;                         // head 0..63
    const int r0  = (vb & 31) << 5;                  // q-row base (32 rows)
    const size_t hb = (size_t)n << 16;               // head base, BYTES (64 KB)
    const int lm = ln & 15, lk = ln >> 4;

    // Q fragments (B operand), both 16-row groups: chunk (n, (r0>>4)+g)
    i32x4 qa[2], qb[2];
#pragma unroll
    for (int g = 0; g < 2; ++g) {
        const size_t qo = hb + ((size_t)((r0 >> 4) + g) << 10) + ((size_t)ln << 4);
        qa[g] = *(const i32x4*)(qA + qo);
        qb[g] = *(const i32x4*)(qB + qo);
    }

    f32x4 acc[2][8];
#pragma unroll
    for (int g = 0; g < 2; ++g)
#pragma unroll
        for (int nf = 0; nf < 8; ++nf) acc[g][nf] = (f32x4){0.f, 0.f, 0.f, 0.f};

    const int c0 = wv * 128;                         // this wave's 128 k-cols
    const i32x4 z4 = (i32x4){0, 0, 0, 0};

#pragma unroll
    for (int nf = 0; nf < 8; ++nf) {
        const size_t ko = hb + ((size_t)((c0 >> 4) + nf) << 10) + ((size_t)ln << 4);
        i32x4 ka = *(const i32x4*)(kA + ko);
        i32x4 kb = *(const i32x4*)(kB + ko);
#pragma unroll
        for (int g = 0; g < 2; ++g) {
            i32x4 paa = __builtin_amdgcn_mfma_i32_16x16x64_i8(ka, qa[g], z4, 0, 0, 0);
            i32x4 t1  = __builtin_amdgcn_mfma_i32_16x16x64_i8(kb, qa[g], z4, 0, 0, 0);
            i32x4 pmx = __builtin_amdgcn_mfma_i32_16x16x64_i8(ka, qb[g], t1, 0, 0, 0);
            i32x4 pbb = __builtin_amdgcn_mfma_i32_16x16x64_i8(kb, qb[g], z4, 0, 0, 0);
            f32x4 z;
#pragma unroll
            for (int e = 0; e < 4; ++e)
                z[e] = QC1 * fmaf((float)pmx[e], 0.00390625f,
                        fmaf((float)pbb[e], 1.52587890625e-05f, (float)paa[e]));
            acc[g][nf] = z;
        }
    }

    // ---- row maxes (both groups, paired chains) ----
    {
        float m0v = acc[0][0][0], m1v = acc[1][0][0];
#pragma unroll
        for (int nf = 0; nf < 8; ++nf)
#pragma unroll
            for (int rg = 0; rg < 4; ++rg) {
                m0v = fmaxf(m0v, acc[0][nf][rg]);
                m1v = fmaxf(m1v, acc[1][nf][rg]);
            }
        m0v = fmaxf(m0v, __shfl_xor(m0v, 16)); m1v = fmaxf(m1v, __shfl_xor(m1v, 16));
        m0v = fmaxf(m0v, __shfl_xor(m0v, 32)); m1v = fmaxf(m1v, __shfl_xor(m1v, 32));
        if (ln < 16) { pm[0][wv][ln] = m0v; pm[1][wv][ln] = m1v; }
    }
    __syncthreads();

    float tau[2];
#pragma unroll
    for (int g = 0; g < 2; ++g) {
        float mx = fmaxf(pm[g][lk][lm], pm[g][lk + 4][lm]);
        mx = fmaxf(mx, __shfl_xor(mx, 16));
        mx = fmaxf(mx, __shfl_xor(mx, 32));
        tau[g] = mx - 1.0f;
    }

    // ---- Michelot from tau0 = rowmax-1, joint over both groups ----
    int buf = 0;
    float koldsum = 0.f;
    for (int it = 0; it < 32; ++it) {
        float sv[2] = {0.f, 0.f}, cv[2] = {0.f, 0.f};
#pragma unroll
        for (int g = 0; g < 2; ++g)
#pragma unroll
            for (int nf = 0; nf < 8; ++nf)
#pragma unroll
                for (int rg = 0; rg < 4; ++rg) {
                    const bool p = acc[g][nf][rg] > tau[g];
                    sv[g] += p ? acc[g][nf][rg] : 0.f;
                    cv[g] += p ? 1.f : 0.f;
                }
#pragma unroll
        for (int g = 0; g < 2; ++g) {
            sv[g] += __shfl_xor(sv[g], 16); cv[g] += __shfl_xor(cv[g], 16);
            sv[g] += __shfl_xor(sv[g], 32); cv[g] += __shfl_xor(cv[g], 32);
        }
        if (ln < 16) {
#pragma unroll
            for (int g = 0; g < 2; ++g) {
                ps[buf][g][wv][ln] = sv[g];
                pc[buf][g][wv][ln] = cv[g];
            }
        }
        __syncthreads();
        float S[2], C[2];
#pragma unroll
        for (int g = 0; g < 2; ++g) {
            float Sg = ps[buf][g][lk][lm] + ps[buf][g][lk + 4][lm];
            float Cg = pc[buf][g][lk][lm] + pc[buf][g][lk + 4][lm];
            Sg += __shfl_xor(Sg, 16); Cg += __shfl_xor(Cg, 16);
            Sg += __shfl_xor(Sg, 32); Cg += __shfl_xor(Cg, 32);
            S[g] = Sg; C[g] = Cg;
        }
        const float csum = C[0] + C[1];
        const bool st = (csum == koldsum);   // both rows stable (non-increasing)
        koldsum = csum;
#pragma unroll
        for (int g = 0; g < 2; ++g)
            tau[g] = (S[g] - 1.0f) / C[g];   // bit-identical when converged
        buf ^= 1;
        if (__all(st)) break;                // block-uniform exit
    }

    // ---- fused relu write: native float4 per accumulator, cached stores ----
#pragma unroll
    for (int g = 0; g < 2; ++g) {
        float* orow = out + ((((size_t)n << 10) + r0 + (g << 4) + lm) << 10)
                          + c0 + (lk << 2);
#pragma unroll
        for (int nf = 0; nf < 8; ++nf) {
            f32x4 o;
            o[0] = fmaxf(acc[g][nf][0] - tau[g], 0.f);
            o[1] = fmaxf(acc[g][nf][1] - tau[g], 0.f);
            o[2] = fmaxf(acc[g][nf][2] - tau[g], 0.f);
            o[3] = fmaxf(acc[g][nf][3] - tau[g], 0.f);
            *(f32x4*)(orow + nf * 16) = o;
        }
    }
}

// ---------------------------------------------------------------------------
extern "C" void kernel_launch(void* const* d_in, const int* in_sizes, int n_in,
                              void* d_out, int out_size, void* d_ws, size_t ws_size,
                              hipStream_t stream) {
    const float* x = (const float*)d_in[0];          // [4096, 1024]
    const float* w = (const float*)d_in[1];          // [3072, 1024]
    float* out = (float*)d_out;                      // [64, 1024, 1024]

    const size_t H8 = (size_t)64 * 65536;            // 4 MB per i8 array
    const size_t XE = (size_t)4096 * 1024;           // x elems
    const size_t WE = (size_t)2048 * 1024;           // W' elems (rows 1024..3071)
    signed char* kA = (signed char*)d_ws;
    signed char* kB = kA + H8;
    signed char* qA = kB + H8;
    signed char* qB = qA + H8;                       // 16 MB i8
    ushort* xh = (ushort*)(qB + H8);
    ushort* xl = xh + XE;
    ushort* wh = xl + XE;
    ushort* wl = wh + WE;                            // + 24 MB bf16 staging

    convert_split2_kernel<<<2048, 256, 0, stream>>>(
        x, xh, xl, (int)(XE / 4),
        w + (size_t)1024 * 1024, wh, wl, (int)(WE / 4));
    proj_kernel<<<dim3(16, 32), 512, 0, stream>>>(xh, xl, wh, wl, kA, kB, qA, qB);
    attn_sparsemax_kernel<<<2048, 512, 0, stream>>>(kA, kB, qA, qB, out);
}